// Round 23
// baseline (184.626 us; speedup 1.0000x reference)
//
#include <hip/hip_runtime.h>
#include <hip/hip_bf16.h>

// ---------------------------------------------------------------------------
// MambaConvBlock fused pipeline. Round 23: scan_pass2_fused re-tiled to
// 32-token blocks (grid 1024, LDS 22KB) for 2x occupancy on the VALU-bound
// scan phase. Rest identical to R22.
// Sizes: B=8, CIN=64, COUT=128, H=W=64, L=4096, T=32768,
//        DINNER=256, DSTATE=16, DTRANK=8, DCONV=4.
// ---------------------------------------------------------------------------

typedef __attribute__((ext_vector_type(8))) short bf16x8;
typedef __attribute__((ext_vector_type(4))) float f32x4;

#define DEV __device__ __forceinline__

constexpr float LOG2E = 1.44269504088896f;

DEV float siluf(float v) {
  return v * __builtin_amdgcn_rcpf(1.f + __expf(-v));
}

DEV unsigned short f2bf(float f) {
  __hip_bfloat16 h = __float2bfloat16(f);
  return *reinterpret_cast<unsigned short*>(&h);
}

DEV float bf2f(unsigned short u) {
  unsigned int x = (unsigned int)u << 16;
  return __builtin_bit_cast(float, x);
}

// async global->LDS, 16B per lane; lds dest = uniform base + lane*16
DEV void gll16(const void* g, void* l) {
  __builtin_amdgcn_global_load_lds(
      (const __attribute__((address_space(1))) void*)g,
      (__attribute__((address_space(3))) void*)l, 16, 0, 0);
}

constexpr int NC = 256;  // scan chunks per batch
constexpr int CL = 16;   // scan chunk length

// ---------------- prologue: nchw->NHWC bf16 + weight prep + border zero -----
DEV void zero_border(unsigned short* buf, int CI, int tid0, int nthreads) {
  for (int w = tid0; w < 8 * 260; w += nthreads) {
    int b = w / 260, e = w % 260;
    int y, x;
    if (e < 132) { y = (e < 66) ? 0 : 65; x = (e < 66) ? e : e - 66; }
    else { int e2 = e - 132; y = 1 + (e2 >> 1); x = (e2 & 1) ? 65 : 0; }
    uint4* p = reinterpret_cast<uint4*>(buf + ((size_t)((b * 66 + y) * 66 + x)) * CI);
    for (int k = 0; k < CI / 8; ++k) p[k] = uint4{0u, 0u, 0u, 0u};
  }
}

__global__ __launch_bounds__(256) void prologue(
    const float* __restrict__ X, unsigned short* __restrict__ Xb,
    const float* __restrict__ conv1_w, const float* __restrict__ conv2_w,
    const float* __restrict__ in_proj_w, const float* __restrict__ out_proj_w,
    const float* __restrict__ x_proj_w, const float* __restrict__ A_log,
    unsigned short* __restrict__ wb1, unsigned short* __restrict__ wb2,
    unsigned short* __restrict__ win, unsigned short* __restrict__ wout,
    unsigned short* __restrict__ xpwb, float* __restrict__ An2f,
    unsigned short* __restrict__ h1p)
{
  __shared__ float t[64][65];
  const int blk = blockIdx.x;
  const int tid = threadIdx.x;
  if (blk < 512) {
    const int b = blk >> 6, y = blk & 63;
    for (int i = tid; i < 4096; i += 256) {
      int c = i >> 6, xx = i & 63;
      t[c][xx] = X[(((size_t)b * 64 + c) * 64 + y) * 64 + xx];
    }
    __syncthreads();
    for (int i = tid; i < 4096; i += 256) {
      int xx = i >> 6, c = i & 63;
      Xb[(((size_t)(b * 66 + y + 1) * 66) + xx + 1) * 64 + c] = f2bf(t[c][xx]);
    }
  } else if (blk < 1904) {
    int idx = (blk - 512) * 256 + tid;
    if (idx < 73728) {
      int co = idx / 576, r = idx % 576, tp = r >> 6, ci = r & 63;
      wb1[idx] = f2bf(conv1_w[((size_t)co * 64 + ci) * 9 + tp]);
    } else if (idx < 221184) {
      int i = idx - 73728;
      int co = i / 1152, r = i % 1152, tp = r >> 7, ci = r & 127;
      wb2[i] = f2bf(conv2_w[((size_t)co * 128 + ci) * 9 + tp]);
    } else if (idx < 286720) {
      int i = idx - 221184; win[i] = f2bf(in_proj_w[i]);
    } else if (idx < 319488) {
      int i = idx - 286720; wout[i] = f2bf(out_proj_w[i]);
    } else if (idx < 352256) {
      int i = idx - 319488; int r = i >> 8, c = i & 255;
      xpwb[i] = (r < 40) ? f2bf(x_proj_w[r * 256 + c]) : (unsigned short)0;
    } else if (idx < 356352) {
      int i = idx - 352256;
      An2f[i] = -__expf(A_log[i]) * LOG2E;
    }
  } else {
    int tid0 = (blk - 1904) * 256 + tid;
    zero_border(Xb, 64, tid0, 16 * 256);
    zero_border(h1p, 128, tid0, 16 * 256);
  }
}

// ---------------- conv3x3 + BN + ReLU: LDS-staged implicit GEMM -------------
template<int CI, int PADOUT>
__global__ __launch_bounds__(512) void conv_mfma(
    const unsigned short* __restrict__ Xp,   // [b][66][66][CI] bf16 padded
    const unsigned short* __restrict__ Wb,   // [128][9*CI]     bf16
    const float* __restrict__ bc,
    const float* __restrict__ bg, const float* __restrict__ bb,
    const float* __restrict__ bm, const float* __restrict__ bv,
    unsigned short* __restrict__ Y)
{
  constexpr int KC  = 3 * CI / 64;
  constexpr int NCH = 3 * KC;
  __shared__ bf16x8 ldsA[2][512];

  const int tid  = threadIdx.x;
  const int lane = tid & 63;
  const int wid  = tid >> 6;          // 0..7
  const int n0 = wid * 16;
  const int y = blockIdx.x, b = blockIdx.y;
  const int lr = lane & 15, kq = lane >> 4, lk = kq * 8;

  auto stage = [&](int buf, int c) {
    const int dy = c / KC, kc = c - dy * KC;
    const unsigned short* g = Xp
        + (size_t)((b * 66 + y + dy) * 66) * CI
        + (size_t)lane * CI + kc * 64 + wid * 8;
    gll16(g, &ldsA[buf][wid * 64]);
  };

  f32x4 acc[4];
  #pragma unroll
  for (int i = 0; i < 4; ++i) acc[i] = f32x4{0.f, 0.f, 0.f, 0.f};

  stage(0, 0);
  __syncthreads();

  #pragma unroll
  for (int c = 0; c < NCH; ++c) {
    if (c + 1 < NCH) stage((c + 1) & 1, c + 1);
    const int dy = c / KC, kc = c - dy * KC;
    bf16x8 bw[2];
    #pragma unroll
    for (int t = 0; t < 2; ++t)
      bw[t] = *reinterpret_cast<const bf16x8*>(
          Wb + (size_t)(n0 + lr) * (9 * CI)
             + dy * 3 * CI + kc * 64 + t * 32 + lk);
    const bf16x8* Ab = ldsA[c & 1];
    #pragma unroll
    for (int t = 0; t < 2; ++t)
      #pragma unroll
      for (int mf = 0; mf < 4; ++mf) {
        bf16x8 afr = Ab[(t * 4 + kq) * 64 + mf * 16 + lr];
        acc[mf] = __builtin_amdgcn_mfma_f32_16x16x32_bf16(
            afr, bw[t], acc[mf], 0, 0, 0);
      }
    __syncthreads();
  }

  {
    int n = n0 + lr;
    float aS = bg[n] * rsqrtf(bv[n] + 1e-5f);
    float aB = (bc[n] - bm[n]) * aS + bb[n];
    #pragma unroll
    for (int mf = 0; mf < 4; ++mf)
      #pragma unroll
      for (int i = 0; i < 4; ++i) {
        int m = mf * 16 + kq * 4 + i;
        float v = fmaxf(acc[mf][i] * aS + aB, 0.f);
        if (PADOUT)
          Y[((size_t)(b * 66 + y + 1) * 66 + m + 1) * 128 + n] = f2bf(v);
        else
          Y[((size_t)(b * 4096 + y * 64 + m)) * 128 + n] = f2bf(v);
      }
  }
}

// ---------------- in_proj GEMM + depthwise conv1d + silu, fused -------------
__global__ __launch_bounds__(256) void inproj_fused(
    const unsigned short* __restrict__ A,    // seqb [T][128] bf16
    const unsigned short* __restrict__ Wn,   // win [512][128] bf16
    const float* __restrict__ c1w,           // conv1d_w (256,4)
    const float* __restrict__ c1b,           // conv1d_b (256)
    unsigned short* __restrict__ xsu,        // (T,256) bf16
    unsigned short* __restrict__ zbu)        // (T,256) bf16 = silu(z)
{
  constexpr int KDIM = 128;
  __shared__ bf16x8 ldsA[2][512];
  __shared__ unsigned short xmt[67][136];
  __shared__ unsigned short s3[3][128];
  __shared__ float cw[128][4];
  __shared__ float cbias[128];

  const int tid = threadIdx.x;
  const int lane = tid & 63, wid = tid >> 6;
  const int m0 = blockIdx.x * 64;
  const int by = blockIdx.y;
  const int n0 = by * 128 + wid * 32;
  const int lr = lane & 15, kq = lane >> 4, lk = kq * 8;
  const int l0 = m0 & 4095;

  if (by < 2) {
    for (int w = tid; w < 384; w += 256) {
      int j = w >> 7, k = w & 127;
      s3[j][k] = (l0 == 0) ? (unsigned short)0
                           : A[(size_t)(m0 - 3 + j) * 128 + k];
    }
    if (tid < 128) {
      int dd = by * 128 + tid;
      cw[tid][0] = c1w[dd * 4 + 0]; cw[tid][1] = c1w[dd * 4 + 1];
      cw[tid][2] = c1w[dd * 4 + 2]; cw[tid][3] = c1w[dd * 4 + 3];
      cbias[tid] = c1b[dd];
    }
  }

  bf16x8 bw[2][2][2];
  #pragma unroll
  for (int c = 0; c < 2; ++c)
    #pragma unroll
    for (int t = 0; t < 2; ++t)
      #pragma unroll
      for (int nf = 0; nf < 2; ++nf)
        bw[c][t][nf] = *reinterpret_cast<const bf16x8*>(
            Wn + (size_t)(n0 + nf * 16 + lr) * KDIM + c * 64 + t * 32 + lk);

  auto stage = [&](int buf, int c) {
    const unsigned short* g = A + (size_t)(m0 + lane) * KDIM + c * 64 + wid * 16;
    gll16(g,     &ldsA[buf][(wid * 2) * 64]);
    gll16(g + 8, &ldsA[buf][(wid * 2 + 1) * 64]);
  };

  f32x4 acc[4][2];
  #pragma unroll
  for (int i = 0; i < 4; ++i)
    #pragma unroll
    for (int j = 0; j < 2; ++j) acc[i][j] = f32x4{0.f, 0.f, 0.f, 0.f};

  stage(0, 0);
  __syncthreads();

  #pragma unroll
  for (int c = 0; c < 2; ++c) {
    if (c + 1 < 2) stage((c + 1) & 1, c + 1);
    const bf16x8* Ab = ldsA[c & 1];
    #pragma unroll
    for (int t = 0; t < 2; ++t)
      #pragma unroll
      for (int mf = 0; mf < 4; ++mf) {
        bf16x8 afr = Ab[(t * 4 + kq) * 64 + mf * 16 + lr];
        #pragma unroll
        for (int nf = 0; nf < 2; ++nf)
          acc[mf][nf] = __builtin_amdgcn_mfma_f32_16x16x32_bf16(
              afr, bw[c][t][nf], acc[mf][nf], 0, 0, 0);
      }
    __syncthreads();
  }

  if (by >= 2) {
    #pragma unroll
    for (int nf = 0; nf < 2; ++nf) {
      int n = n0 + nf * 16 + lr - 256;
      #pragma unroll
      for (int mf = 0; mf < 4; ++mf)
        #pragma unroll
        for (int i = 0; i < 4; ++i)
          zbu[(size_t)(m0 + mf * 16 + kq * 4 + i) * 256 + n] =
              f2bf(siluf(acc[mf][nf][i]));
    }
    return;
  }

  #pragma unroll
  for (int nf = 0; nf < 2; ++nf) {
    int ch = wid * 32 + nf * 16 + lr;
    #pragma unroll
    for (int mf = 0; mf < 4; ++mf)
      #pragma unroll
      for (int i = 0; i < 4; ++i)
        xmt[3 + mf * 16 + kq * 4 + i][ch] = f2bf(acc[mf][nf][i]);
  }
  __syncthreads();

  for (int w = tid; w < 384; w += 256) {
    int j = w >> 7, ch = w & 127;
    float a = 0.f;
    if (l0 != 0) {
      const unsigned short* wr = Wn + (size_t)(by * 128 + ch) * 128;
      #pragma unroll 4
      for (int k0 = 0; k0 < 128; k0 += 8) {
        bf16x8 wv = *reinterpret_cast<const bf16x8*>(wr + k0);
        #pragma unroll
        for (int k = 0; k < 8; ++k)
          a = fmaf(bf2f(s3[j][k0 + k]), bf2f((unsigned short)wv[k]), a);
      }
    }
    xmt[j][ch] = f2bf(a);
  }
  __syncthreads();

  const int tg = tid & 15, ch8 = tid >> 4;
  float wr8[8][4], br8[8];
  #pragma unroll
  for (int k = 0; k < 8; ++k) {
    int chl = ch8 * 8 + k;
    wr8[k][0] = cw[chl][0]; wr8[k][1] = cw[chl][1];
    wr8[k][2] = cw[chl][2]; wr8[k][3] = cw[chl][3];
    br8[k] = cbias[chl];
  }
  #pragma unroll
  for (int tk = 0; tk < 4; ++tk) {
    int m = tg * 4 + tk;
    float o[8];
    #pragma unroll
    for (int k = 0; k < 8; ++k) o[k] = br8[k];
    #pragma unroll
    for (int j = 0; j < 4; ++j) {
      uint4 xv = *reinterpret_cast<const uint4*>(&xmt[m + j][ch8 * 8]);
      const unsigned short* xs = reinterpret_cast<const unsigned short*>(&xv);
      #pragma unroll
      for (int k = 0; k < 8; ++k)
        o[k] = fmaf(bf2f(xs[k]), wr8[k][j], o[k]);
    }
    unsigned int pk[4];
    #pragma unroll
    for (int k = 0; k < 4; ++k) {
      unsigned short lo = f2bf(siluf(o[2 * k]));
      unsigned short hi = f2bf(siluf(o[2 * k + 1]));
      pk[k] = (unsigned int)lo | ((unsigned int)hi << 16);
    }
    *reinterpret_cast<uint4*>(
        &xsu[(size_t)(m0 + m) * 256 + by * 128 + ch8 * 8]) =
        *reinterpret_cast<uint4*>(pk);
  }
}

// ---------------- chunked selective scan ------------------------------------
// pass1: inline x_proj (MFMA) -> sh, writes sh to xdb; tree-power dA.
__global__ __launch_bounds__(256) void scan_pass1(
    const unsigned short* __restrict__ xssm,
    const unsigned short* __restrict__ xpw,   // [128][256] bf16, rows>=40 zero
    const float* __restrict__ dtw, const float* __restrict__ dtb,
    const float* __restrict__ An2f,
    unsigned short* __restrict__ Qb, float* __restrict__ S,
    float* __restrict__ xdb)                  // (T,40) f32 out
{
  __shared__ __align__(16) float sh[CL][40];
  const int c = blockIdx.x, b = blockIdx.y;
  const int d = threadIdx.x;
  const int lane = threadIdx.x & 63, wid = threadIdx.x >> 6;
  if (wid < 3) {
    const int col0 = wid * 16;
    const int plr = lane & 15, plk = (lane >> 4) * 8;
    f32x4 pacc = f32x4{0.f, 0.f, 0.f, 0.f};
    const unsigned short* Xrow =
        xssm + ((size_t)b * 4096 + (size_t)c * CL + plr) * 256;
    const unsigned short* Wrow = xpw + (size_t)(col0 + plr) * 256;
    #pragma unroll
    for (int k0 = 0; k0 < 256; k0 += 32) {
      bf16x8 af = *reinterpret_cast<const bf16x8*>(Xrow + k0 + plk);
      bf16x8 bf = *reinterpret_cast<const bf16x8*>(Wrow + k0 + plk);
      pacc = __builtin_amdgcn_mfma_f32_16x16x32_bf16(af, bf, pacc, 0, 0, 0);
    }
    int col = col0 + (lane & 15);
    if (col < 40) {
      #pragma unroll
      for (int i = 0; i < 4; ++i)
        sh[(lane >> 4) * 4 + i][col] = pacc[i];
    }
  }
  float4 w0 = *reinterpret_cast<const float4*>(&dtw[d * 8]);
  float4 w1 = *reinterpret_cast<const float4*>(&dtw[d * 8 + 4]);
  const float bdt = dtb[d];
  float An2[16], h[16];
  {
    const f32x4* a2 = reinterpret_cast<const f32x4*>(&An2f[d * 16]);
    #pragma unroll
    for (int q = 0; q < 4; ++q) {
      f32x4 v = a2[q];
      An2[q * 4 + 0] = v[0]; An2[q * 4 + 1] = v[1];
      An2[q * 4 + 2] = v[2]; An2[q * 4 + 3] = v[3];
    }
  }
  const float An2_0 = An2[0];
  bool usePow = true;
  #pragma unroll
  for (int s = 1; s < 16; ++s)
    usePow = usePow &&
        (fabsf(An2[s] - (float)(s + 1) * An2_0) <= 1e-4f * fabsf(An2[s]));
  #pragma unroll
  for (int s = 0; s < 16; ++s) h[s] = 0.f;
  __syncthreads();

  // persist sh tile for pass2 (de-dup x_proj)
  if (d < CL * 10) {
    reinterpret_cast<float4*>(&xdb[((size_t)b * 4096 + (size_t)c * CL) * 40])[d] =
        reinterpret_cast<const float4*>(&sh[0][0])[d];
  }

  float sdt = 0.f;
  const size_t xbase = ((size_t)b * 4096 + (size_t)c * CL) * 256 + d;
  unsigned short xu = xssm[xbase];
  for (int l = 0; l < CL; ++l) {
    unsigned short xun = (l + 1 < CL) ? xssm[xbase + (size_t)(l + 1) * 256]
                                      : (unsigned short)0;
    const float4* row = reinterpret_cast<const float4*>(sh[l]);
    float4 r0 = row[0], r1 = row[1];
    float acc = bdt;
    acc = fmaf(r0.x, w0.x, acc); acc = fmaf(r0.y, w0.y, acc);
    acc = fmaf(r0.z, w0.z, acc); acc = fmaf(r0.w, w0.w, acc);
    acc = fmaf(r1.x, w1.x, acc); acc = fmaf(r1.y, w1.y, acc);
    acc = fmaf(r1.z, w1.z, acc); acc = fmaf(r1.w, w1.w, acc);
    float dt = (acc > 20.f) ? acc : __logf(1.f + __expf(acc));
    sdt += dt;
    float dtx = dt * bf2f(xu);
    if (usePow) {
      float r1p = __builtin_amdgcn_exp2f(dt * An2_0);
      float r2 = r1p * r1p, r3 = r2 * r1p, r4 = r2 * r2;
      float pj[4] = {r1p, r2, r3, r4};
      float base = 1.f;
      #pragma unroll
      for (int q = 0; q < 4; ++q) {
        float4 Bq = row[2 + q];
        float bb4[4] = {Bq.x, Bq.y, Bq.z, Bq.w};
        #pragma unroll
        for (int j = 0; j < 4; ++j) {
          int s = q * 4 + j;
          h[s] = fmaf(base * pj[j], h[s], dtx * bb4[j]);
        }
        base *= r4;
      }
    } else {
      #pragma unroll
      for (int q = 0; q < 4; ++q) {
        float4 Bq = row[2 + q];
        float bb4[4] = {Bq.x, Bq.y, Bq.z, Bq.w};
        #pragma unroll
        for (int j = 0; j < 4; ++j) {
          int s = q * 4 + j;
          float dA = __builtin_amdgcn_exp2f(dt * An2[s]);
          h[s] = fmaf(dA, h[s], dtx * bb4[j]);
        }
      }
    }
    xu = xun;
  }
  unsigned int pk[8];
  #pragma unroll
  for (int k = 0; k < 8; ++k)
    pk[k] = (unsigned int)f2bf(h[2 * k]) | ((unsigned int)f2bf(h[2 * k + 1]) << 16);
  uint4* qp = reinterpret_cast<uint4*>(
      &Qb[(((size_t)b * NC + c) * 256 + d) * 16]);
  qp[0] = *reinterpret_cast<uint4*>(pk);
  qp[1] = *reinterpret_cast<uint4*>(pk + 4);
  S[((size_t)b * NC + c) * 256 + d] = sdt;
}

// ---------------- coalesced LDS-buffered combine ----------------------------
__global__ __launch_bounds__(256) void scan_combine(
    unsigned short* __restrict__ Qb, const float* __restrict__ S,
    const float* __restrict__ An2f)
{
  constexpr int TC = 64;
  __shared__ unsigned short qt[TC][256];
  __shared__ float mt[TC][256];
  const int b = blockIdx.x >> 4, dsg = blockIdx.x & 15;
  const int tid = threadIdx.x;
  const int ds = dsg * 256 + tid;      // d*16+s
  const int d = ds >> 4;
  const float An2 = An2f[ds];
  float h = 0.f;
  for (int ct = 0; ct < NC; ct += TC) {
    #pragma unroll 8
    for (int r = 0; r < TC; ++r) {
      int c = ct + r;
      qt[r][tid] = Qb[(size_t)(b * NC + c) * 4096 + ds];
      mt[r][tid] = __builtin_amdgcn_exp2f(
          An2 * S[(size_t)(b * NC + c) * 256 + d]);
    }
    #pragma unroll 8
    for (int r = 0; r < TC; ++r) {
      float q = bf2f(qt[r][tid]);
      qt[r][tid] = f2bf(h);
      h = fmaf(mt[r][tid], h, q);
    }
    #pragma unroll 8
    for (int r = 0; r < TC; ++r)
      Qb[(size_t)(b * NC + ct + r) * 4096 + ds] = qt[r][tid];
  }
}

// ---------------- pass2 + out_proj + LN + NCHW transpose, fused -------------
// Grid (128, 8), 512 threads. Block covers 2 chunks = 32 tokens of batch b.
// Scan: each 256-thread half scans ONE chunk; y -> LDS ybuf[32][264] bf16.
// GEMM: 8 waves, N=16/wave, M=32, K=256 from ybuf; LN (16 thr/token);
// NCHW write. fp32 LN buf[32][132] ALIASES ybuf (16,896 B each, barriers).
__global__ __launch_bounds__(512) void scan_pass2_fused(
    const unsigned short* __restrict__ xssm,
    const float* __restrict__ xdb,           // (T,40) f32 from pass1
    const unsigned short* __restrict__ zb,   // silu(z) bf16
    const float* __restrict__ dtw, const float* __restrict__ dtb,
    const float* __restrict__ An2f, const float* __restrict__ Dp,
    const unsigned short* __restrict__ Hstart,  // Qb (bf16 h_start)
    const unsigned short* __restrict__ Wn,      // wout [128][256] bf16
    const float* __restrict__ lg, const float* __restrict__ lb,
    float* __restrict__ out)                    // [8][128][64][64]
{
  __shared__ __align__(16) float sh[2][CL][40];        // 5,120 B
  __shared__ __align__(16) char yb_raw[32 * 264 * 2];  // 16,896 B (ybuf|buf)
  unsigned short (*ybuf)[264] =
      reinterpret_cast<unsigned short(*)[264]>(yb_raw);
  float (*buf)[132] = reinterpret_cast<float(*)[132]>(yb_raw);

  const int cg = blockIdx.x, b = blockIdx.y;   // cg 0..127
  const int c0 = cg * 2;
  const int tid = threadIdx.x;
  const int lane = tid & 63, wid = tid >> 6;
  const int d = tid & 255;
  const int half = tid >> 8;

  // stage 2 chunk xdb tiles (320 float4)
  for (int i = tid; i < 2 * CL * 10; i += 512) {
    reinterpret_cast<float4*>(&sh[0][0][0])[i] =
        reinterpret_cast<const float4*>(
            &xdb[((size_t)b * 4096 + (size_t)c0 * CL) * 40])[i];
  }

  float4 w0 = *reinterpret_cast<const float4*>(&dtw[d * 8]);
  float4 w1 = *reinterpret_cast<const float4*>(&dtw[d * 8 + 4]);
  const float bdt = dtb[d];
  const float Dd = Dp[d];
  float An2[16];
  {
    const f32x4* a2 = reinterpret_cast<const f32x4*>(&An2f[d * 16]);
    #pragma unroll
    for (int q = 0; q < 4; ++q) {
      f32x4 v = a2[q];
      An2[q * 4 + 0] = v[0]; An2[q * 4 + 1] = v[1];
      An2[q * 4 + 2] = v[2]; An2[q * 4 + 3] = v[3];
    }
  }
  const float An2_0 = An2[0];
  bool usePow = true;
  #pragma unroll
  for (int s = 1; s < 16; ++s)
    usePow = usePow &&
        (fabsf(An2[s] - (float)(s + 1) * An2_0) <= 1e-4f * fabsf(An2[s]));
  __syncthreads();

  // ---- scan phase: half h scans chunk c0+half ----
  {
    const int ch = half;
    const int c = c0 + ch;
    float h[16];
    {
      const uint4* hp = reinterpret_cast<const uint4*>(
          &Hstart[(((size_t)b * NC + c) * 256 + d) * 16]);
      uint4 h0 = hp[0], h1 = hp[1];
      const unsigned short* hs = reinterpret_cast<const unsigned short*>(&h0);
      #pragma unroll
      for (int s = 0; s < 8; ++s) h[s] = bf2f(hs[s]);
      const unsigned short* hs2 = reinterpret_cast<const unsigned short*>(&h1);
      #pragma unroll
      for (int s = 0; s < 8; ++s) h[8 + s] = bf2f(hs2[s]);
    }
    const size_t xbase = ((size_t)b * 4096 + (size_t)c * CL) * 256 + d;
    unsigned short xu = xssm[xbase], zu = zb[xbase];
    for (int l = 0; l < CL; ++l) {
      unsigned short xun = 0, zun = 0;
      if (l + 1 < CL) {
        xun = xssm[xbase + (size_t)(l + 1) * 256];
        zun = zb[xbase + (size_t)(l + 1) * 256];
      }
      const float4* row = reinterpret_cast<const float4*>(sh[ch][l]);
      float4 r0 = row[0], r1 = row[1];
      float acc = bdt;
      acc = fmaf(r0.x, w0.x, acc); acc = fmaf(r0.y, w0.y, acc);
      acc = fmaf(r0.z, w0.z, acc); acc = fmaf(r0.w, w0.w, acc);
      acc = fmaf(r1.x, w1.x, acc); acc = fmaf(r1.y, w1.y, acc);
      acc = fmaf(r1.z, w1.z, acc); acc = fmaf(r1.w, w1.w, acc);
      float dt = (acc > 20.f) ? acc : __logf(1.f + __expf(acc));
      float xv = bf2f(xu);
      float dtx = dt * xv;
      float yq[4] = {0.f, 0.f, 0.f, 0.f};
      if (usePow) {
        float r1p = __builtin_amdgcn_exp2f(dt * An2_0);
        float r2 = r1p * r1p, r3 = r2 * r1p, r4 = r2 * r2;
        float pj[4] = {r1p, r2, r3, r4};
        float base = 1.f;
        #pragma unroll
        for (int q = 0; q < 4; ++q) {
          float4 Bq = row[2 + q], Cq = row[6 + q];
          float bb4[4] = {Bq.x, Bq.y, Bq.z, Bq.w};
          float cc4[4] = {Cq.x, Cq.y, Cq.z, Cq.w};
          #pragma unroll
          for (int j = 0; j < 4; ++j) {
            int s = q * 4 + j;
            h[s] = fmaf(base * pj[j], h[s], dtx * bb4[j]);
            yq[q] = fmaf(h[s], cc4[j], yq[q]);
          }
          base *= r4;
        }
      } else {
        #pragma unroll
        for (int q = 0; q < 4; ++q) {
          float4 Bq = row[2 + q], Cq = row[6 + q];
          float bb4[4] = {Bq.x, Bq.y, Bq.z, Bq.w};
          float cc4[4] = {Cq.x, Cq.y, Cq.z, Cq.w};
          #pragma unroll
          for (int j = 0; j < 4; ++j) {
            int s = q * 4 + j;
            float dA = __builtin_amdgcn_exp2f(dt * An2[s]);
            h[s] = fmaf(dA, h[s], dtx * bb4[j]);
            yq[q] = fmaf(h[s], cc4[j], yq[q]);
          }
        }
      }
      float y = (yq[0] + yq[1]) + (yq[2] + yq[3]);
      y = (y + Dd * xv) * bf2f(zu);   // z already silu'd
      ybuf[ch * CL + l][d] = f2bf(y);
      xu = xun; zu = zun;
    }
  }
  __syncthreads();

  // ---- out_proj GEMM: 8 waves, wave w -> N cols [w*16, w*16+16), M=32 ----
  const int n0g = wid * 16;
  const int lr = lane & 15, kq = lane >> 4, lk = kq * 8;
  bf16x8 bwv[4][2];
  #pragma unroll
  for (int c = 0; c < 4; ++c)
    #pragma unroll
    for (int t = 0; t < 2; ++t)
      bwv[c][t] = *reinterpret_cast<const bf16x8*>(
          Wn + (size_t)(n0g + lr) * 256 + c * 64 + t * 32 + lk);

  f32x4 acc[2];
  #pragma unroll
  for (int i = 0; i < 2; ++i) acc[i] = f32x4{0.f, 0.f, 0.f, 0.f};
  #pragma unroll
  for (int c = 0; c < 4; ++c)
    #pragma unroll
    for (int t = 0; t < 2; ++t) {
      const int kc = c * 64 + t * 32 + lk;
      #pragma unroll
      for (int mf = 0; mf < 2; ++mf) {
        bf16x8 afr = *reinterpret_cast<const bf16x8*>(&ybuf[mf * 16 + lr][kc]);
        acc[mf] = __builtin_amdgcn_mfma_f32_16x16x32_bf16(
            afr, bwv[c][t], acc[mf], 0, 0, 0);
      }
    }
  __syncthreads();

  // ---- write acc into fp32 buf (aliases ybuf; all reads done) ----
  {
    int n = n0g + lr;
    #pragma unroll
    for (int mf = 0; mf < 2; ++mf)
      #pragma unroll
      for (int i = 0; i < 4; ++i)
        buf[mf * 16 + kq * 4 + i][n] = acc[mf][i];
  }
  __syncthreads();

  // ---- LayerNorm: 16 threads/token x 8 ch ----
  {
    const int tt = tid >> 4, q = tid & 15;
    float s = 0.f, sq = 0.f;
    #pragma unroll
    for (int i = 0; i < 8; ++i) {
      float v = buf[tt][q * 8 + i];
      s += v; sq += v * v;
    }
    s  += __shfl_xor(s, 1);  s  += __shfl_xor(s, 2);
    s  += __shfl_xor(s, 4);  s  += __shfl_xor(s, 8);
    sq += __shfl_xor(sq, 1); sq += __shfl_xor(sq, 2);
    sq += __shfl_xor(sq, 4); sq += __shfl_xor(sq, 8);
    float mu = s * (1.f / 128.f);
    float var = sq * (1.f / 128.f) - mu * mu;
    float rstd = rsqrtf(fmaxf(var, 0.f) + 1e-5f);
    #pragma unroll
    for (int i = 0; i < 8; ++i) {
      int ch = q * 8 + i;
      buf[tt][ch] = (buf[tt][ch] - mu) * rstd * lg[ch] + lb[ch];
    }
  }
  __syncthreads();

  // ---- NCHW write (coalesced over 32 consecutive l) ----
  const int l0 = cg * 32;
  for (int idx = tid; idx < 32 * 128; idx += 512) {
    int ch = idx >> 5, t2 = idx & 31;
    out[((size_t)b * 128 + ch) * 4096 + l0 + t2] = buf[t2][ch];
  }
}

// ---------------------------------------------------------------------------
extern "C" void kernel_launch(void* const* d_in, const int* in_sizes, int n_in,
                              void* d_out, int out_size, void* d_ws, size_t ws_size,
                              hipStream_t stream) {
  const float* x        = (const float*)d_in[0];
  const float* conv1_w  = (const float*)d_in[1];
  const float* conv1_b  = (const float*)d_in[2];
  const float* bn1_g    = (const float*)d_in[3];
  const float* bn1_b    = (const float*)d_in[4];
  const float* bn1_m    = (const float*)d_in[5];
  const float* bn1_v    = (const float*)d_in[6];
  const float* conv2_w  = (const float*)d_in[7];
  const float* conv2_b  = (const float*)d_in[8];
  const float* bn2_g    = (const float*)d_in[9];
  const float* bn2_b    = (const float*)d_in[10];
  const float* bn2_m    = (const float*)d_in[11];
  const float* bn2_v    = (const float*)d_in[12];
  const float* in_proj_w  = (const float*)d_in[13];  // (512,128)
  const float* conv1d_w   = (const float*)d_in[14];  // (256,1,4)
  const float* conv1d_b   = (const float*)d_in[15];
  const float* x_proj_w   = (const float*)d_in[16];  // (40,256)
  const float* dt_proj_w  = (const float*)d_in[17];  // (256,8)
  const float* dt_proj_b  = (const float*)d_in[18];
  const float* A_log      = (const float*)d_in[19];  // (256,16)
  const float* Dp         = (const float*)d_in[20];  // (256)
  const float* out_proj_w = (const float*)d_in[21];  // (128,256)
  const float* ln_g       = (const float*)d_in[22];
  const float* ln_b       = (const float*)d_in[23];
  float* out = (float*)d_out;

  float* ws_f = (float*)d_ws;
  // workspace (float units), lifetime-reuse
  unsigned short* xbp  = (unsigned short*)ws_f;          // [8][66][66][64] (pre)
  float*          xdb  = ws_f + 4194304;                 // T*40 f32 (pass1->pass2)
  float*          Sbuf = ws_f + 5505024;                 // B*NC*256 f32
  unsigned short* zbu  = (unsigned short*)(ws_f + 8388608);   // T*256 bf16 silu(z)
  unsigned short* xsu  = (unsigned short*)(ws_f + 12582912);  // T*256 bf16
  unsigned short* h1p  = (unsigned short*)(ws_f + 16777216);  // [8][66][66][128]
  unsigned short* seqb = (unsigned short*)(ws_f + 19007488);  // [T][128]
  unsigned short* Qb   = (unsigned short*)(ws_f + 16777216);  // B*NC*256*16 bf16
  unsigned short* wb1  = (unsigned short*)(ws_f + 25165824);
  unsigned short* wb2  = (unsigned short*)(ws_f + 25202688);
  unsigned short* win  = (unsigned short*)(ws_f + 25276416);
  unsigned short* wout = (unsigned short*)(ws_f + 25309184);
  unsigned short* xpwb = (unsigned short*)(ws_f + 25325568);
  float*          An2f = ws_f + 25341952;

  prologue<<<1920, 256, 0, stream>>>(
      x, xbp, conv1_w, conv2_w, in_proj_w, out_proj_w, x_proj_w, A_log,
      wb1, wb2, win, wout, xpwb, An2f, h1p);

  conv_mfma<64, 1><<<dim3(64, 8), 512, 0, stream>>>(
      xbp, wb1, conv1_b, bn1_g, bn1_b, bn1_m, bn1_v, h1p);
  conv_mfma<128, 0><<<dim3(64, 8), 512, 0, stream>>>(
      h1p, wb2, conv2_b, bn2_g, bn2_b, bn2_m, bn2_v, seqb);

  inproj_fused<<<dim3(512, 4), 256, 0, stream>>>(
      seqb, win, conv1d_w, conv1d_b, xsu, zbu);

  scan_pass1<<<dim3(NC, 8), 256, 0, stream>>>(
      xsu, xpwb, dt_proj_w, dt_proj_b, An2f, Qb, Sbuf, xdb);
  scan_combine<<<128, 256, 0, stream>>>(Qb, Sbuf, An2f);
  scan_pass2_fused<<<dim3(128, 8), 512, 0, stream>>>(
      xsu, xdb, zbu, dt_proj_w, dt_proj_b, An2f, Dp, Qb,
      wout, ln_g, ln_b, out);
}

// Round 24
// 183.039 us; speedup vs baseline: 1.0087x; 1.0087x over previous
//
#include <hip/hip_runtime.h>
#include <hip/hip_bf16.h>

// ---------------------------------------------------------------------------
// MambaConvBlock fused pipeline. Round 24 (final): lock-in of the best
// measured configuration (R20, 183.1 us). 6 dispatches:
//   prologue | conv1 | conv2 | inproj_fused | scan_pass1 | combine |
//   scan_pass2+out_proj+LN+transpose (fused).
// Scan is VALU-issue-bound (~58% busy, HBM 13%, plateau across ILP/TLP
// variants R21-R23); further gains would need an SSD/MFMA reformulation
// with documented overflow hazards.
// Sizes: B=8, CIN=64, COUT=128, H=W=64, L=4096, T=32768,
//        DINNER=256, DSTATE=16, DTRANK=8, DCONV=4.
// ---------------------------------------------------------------------------

typedef __attribute__((ext_vector_type(8))) short bf16x8;
typedef __attribute__((ext_vector_type(4))) float f32x4;

#define DEV __device__ __forceinline__

constexpr float LOG2E = 1.44269504088896f;

DEV float siluf(float v) {
  return v * __builtin_amdgcn_rcpf(1.f + __expf(-v));
}

DEV unsigned short f2bf(float f) {
  __hip_bfloat16 h = __float2bfloat16(f);
  return *reinterpret_cast<unsigned short*>(&h);
}

DEV float bf2f(unsigned short u) {
  unsigned int x = (unsigned int)u << 16;
  return __builtin_bit_cast(float, x);
}

// async global->LDS, 16B per lane; lds dest = uniform base + lane*16
DEV void gll16(const void* g, void* l) {
  __builtin_amdgcn_global_load_lds(
      (const __attribute__((address_space(1))) void*)g,
      (__attribute__((address_space(3))) void*)l, 16, 0, 0);
}

constexpr int NC = 256;  // scan chunks per batch
constexpr int CL = 16;   // scan chunk length

// ---------------- prologue: nchw->NHWC bf16 + weight prep + border zero -----
DEV void zero_border(unsigned short* buf, int CI, int tid0, int nthreads) {
  for (int w = tid0; w < 8 * 260; w += nthreads) {
    int b = w / 260, e = w % 260;
    int y, x;
    if (e < 132) { y = (e < 66) ? 0 : 65; x = (e < 66) ? e : e - 66; }
    else { int e2 = e - 132; y = 1 + (e2 >> 1); x = (e2 & 1) ? 65 : 0; }
    uint4* p = reinterpret_cast<uint4*>(buf + ((size_t)((b * 66 + y) * 66 + x)) * CI);
    for (int k = 0; k < CI / 8; ++k) p[k] = uint4{0u, 0u, 0u, 0u};
  }
}

__global__ __launch_bounds__(256) void prologue(
    const float* __restrict__ X, unsigned short* __restrict__ Xb,
    const float* __restrict__ conv1_w, const float* __restrict__ conv2_w,
    const float* __restrict__ in_proj_w, const float* __restrict__ out_proj_w,
    const float* __restrict__ x_proj_w, const float* __restrict__ A_log,
    unsigned short* __restrict__ wb1, unsigned short* __restrict__ wb2,
    unsigned short* __restrict__ win, unsigned short* __restrict__ wout,
    unsigned short* __restrict__ xpwb, float* __restrict__ An2f,
    unsigned short* __restrict__ h1p)
{
  __shared__ float t[64][65];
  const int blk = blockIdx.x;
  const int tid = threadIdx.x;
  if (blk < 512) {
    const int b = blk >> 6, y = blk & 63;
    for (int i = tid; i < 4096; i += 256) {
      int c = i >> 6, xx = i & 63;
      t[c][xx] = X[(((size_t)b * 64 + c) * 64 + y) * 64 + xx];
    }
    __syncthreads();
    for (int i = tid; i < 4096; i += 256) {
      int xx = i >> 6, c = i & 63;
      Xb[(((size_t)(b * 66 + y + 1) * 66) + xx + 1) * 64 + c] = f2bf(t[c][xx]);
    }
  } else if (blk < 1904) {
    int idx = (blk - 512) * 256 + tid;
    if (idx < 73728) {
      int co = idx / 576, r = idx % 576, tp = r >> 6, ci = r & 63;
      wb1[idx] = f2bf(conv1_w[((size_t)co * 64 + ci) * 9 + tp]);
    } else if (idx < 221184) {
      int i = idx - 73728;
      int co = i / 1152, r = i % 1152, tp = r >> 7, ci = r & 127;
      wb2[i] = f2bf(conv2_w[((size_t)co * 128 + ci) * 9 + tp]);
    } else if (idx < 286720) {
      int i = idx - 221184; win[i] = f2bf(in_proj_w[i]);
    } else if (idx < 319488) {
      int i = idx - 286720; wout[i] = f2bf(out_proj_w[i]);
    } else if (idx < 352256) {
      int i = idx - 319488; int r = i >> 8, c = i & 255;
      xpwb[i] = (r < 40) ? f2bf(x_proj_w[r * 256 + c]) : (unsigned short)0;
    } else if (idx < 356352) {
      int i = idx - 352256;
      An2f[i] = -__expf(A_log[i]) * LOG2E;
    }
  } else {
    int tid0 = (blk - 1904) * 256 + tid;
    zero_border(Xb, 64, tid0, 16 * 256);
    zero_border(h1p, 128, tid0, 16 * 256);
  }
}

// ---------------- conv3x3 + BN + ReLU: LDS-staged implicit GEMM -------------
template<int CI, int PADOUT>
__global__ __launch_bounds__(512) void conv_mfma(
    const unsigned short* __restrict__ Xp,   // [b][66][66][CI] bf16 padded
    const unsigned short* __restrict__ Wb,   // [128][9*CI]     bf16
    const float* __restrict__ bc,
    const float* __restrict__ bg, const float* __restrict__ bb,
    const float* __restrict__ bm, const float* __restrict__ bv,
    unsigned short* __restrict__ Y)
{
  constexpr int KC  = 3 * CI / 64;
  constexpr int NCH = 3 * KC;
  __shared__ bf16x8 ldsA[2][512];

  const int tid  = threadIdx.x;
  const int lane = tid & 63;
  const int wid  = tid >> 6;          // 0..7
  const int n0 = wid * 16;
  const int y = blockIdx.x, b = blockIdx.y;
  const int lr = lane & 15, kq = lane >> 4, lk = kq * 8;

  auto stage = [&](int buf, int c) {
    const int dy = c / KC, kc = c - dy * KC;
    const unsigned short* g = Xp
        + (size_t)((b * 66 + y + dy) * 66) * CI
        + (size_t)lane * CI + kc * 64 + wid * 8;
    gll16(g, &ldsA[buf][wid * 64]);
  };

  f32x4 acc[4];
  #pragma unroll
  for (int i = 0; i < 4; ++i) acc[i] = f32x4{0.f, 0.f, 0.f, 0.f};

  stage(0, 0);
  __syncthreads();

  #pragma unroll
  for (int c = 0; c < NCH; ++c) {
    if (c + 1 < NCH) stage((c + 1) & 1, c + 1);
    const int dy = c / KC, kc = c - dy * KC;
    bf16x8 bw[2];
    #pragma unroll
    for (int t = 0; t < 2; ++t)
      bw[t] = *reinterpret_cast<const bf16x8*>(
          Wb + (size_t)(n0 + lr) * (9 * CI)
             + dy * 3 * CI + kc * 64 + t * 32 + lk);
    const bf16x8* Ab = ldsA[c & 1];
    #pragma unroll
    for (int t = 0; t < 2; ++t)
      #pragma unroll
      for (int mf = 0; mf < 4; ++mf) {
        bf16x8 afr = Ab[(t * 4 + kq) * 64 + mf * 16 + lr];
        acc[mf] = __builtin_amdgcn_mfma_f32_16x16x32_bf16(
            afr, bw[t], acc[mf], 0, 0, 0);
      }
    __syncthreads();
  }

  {
    int n = n0 + lr;
    float aS = bg[n] * rsqrtf(bv[n] + 1e-5f);
    float aB = (bc[n] - bm[n]) * aS + bb[n];
    #pragma unroll
    for (int mf = 0; mf < 4; ++mf)
      #pragma unroll
      for (int i = 0; i < 4; ++i) {
        int m = mf * 16 + kq * 4 + i;
        float v = fmaxf(acc[mf][i] * aS + aB, 0.f);
        if (PADOUT)
          Y[((size_t)(b * 66 + y + 1) * 66 + m + 1) * 128 + n] = f2bf(v);
        else
          Y[((size_t)(b * 4096 + y * 64 + m)) * 128 + n] = f2bf(v);
      }
  }
}

// ---------------- in_proj GEMM + depthwise conv1d + silu, fused -------------
__global__ __launch_bounds__(256) void inproj_fused(
    const unsigned short* __restrict__ A,    // seqb [T][128] bf16
    const unsigned short* __restrict__ Wn,   // win [512][128] bf16
    const float* __restrict__ c1w,           // conv1d_w (256,4)
    const float* __restrict__ c1b,           // conv1d_b (256)
    unsigned short* __restrict__ xsu,        // (T,256) bf16
    unsigned short* __restrict__ zbu)        // (T,256) bf16 = silu(z)
{
  constexpr int KDIM = 128;
  __shared__ bf16x8 ldsA[2][512];
  __shared__ unsigned short xmt[67][136];
  __shared__ unsigned short s3[3][128];
  __shared__ float cw[128][4];
  __shared__ float cbias[128];

  const int tid = threadIdx.x;
  const int lane = tid & 63, wid = tid >> 6;
  const int m0 = blockIdx.x * 64;
  const int by = blockIdx.y;
  const int n0 = by * 128 + wid * 32;
  const int lr = lane & 15, kq = lane >> 4, lk = kq * 8;
  const int l0 = m0 & 4095;

  if (by < 2) {
    for (int w = tid; w < 384; w += 256) {
      int j = w >> 7, k = w & 127;
      s3[j][k] = (l0 == 0) ? (unsigned short)0
                           : A[(size_t)(m0 - 3 + j) * 128 + k];
    }
    if (tid < 128) {
      int dd = by * 128 + tid;
      cw[tid][0] = c1w[dd * 4 + 0]; cw[tid][1] = c1w[dd * 4 + 1];
      cw[tid][2] = c1w[dd * 4 + 2]; cw[tid][3] = c1w[dd * 4 + 3];
      cbias[tid] = c1b[dd];
    }
  }

  bf16x8 bw[2][2][2];
  #pragma unroll
  for (int c = 0; c < 2; ++c)
    #pragma unroll
    for (int t = 0; t < 2; ++t)
      #pragma unroll
      for (int nf = 0; nf < 2; ++nf)
        bw[c][t][nf] = *reinterpret_cast<const bf16x8*>(
            Wn + (size_t)(n0 + nf * 16 + lr) * KDIM + c * 64 + t * 32 + lk);

  auto stage = [&](int buf, int c) {
    const unsigned short* g = A + (size_t)(m0 + lane) * KDIM + c * 64 + wid * 16;
    gll16(g,     &ldsA[buf][(wid * 2) * 64]);
    gll16(g + 8, &ldsA[buf][(wid * 2 + 1) * 64]);
  };

  f32x4 acc[4][2];
  #pragma unroll
  for (int i = 0; i < 4; ++i)
    #pragma unroll
    for (int j = 0; j < 2; ++j) acc[i][j] = f32x4{0.f, 0.f, 0.f, 0.f};

  stage(0, 0);
  __syncthreads();

  #pragma unroll
  for (int c = 0; c < 2; ++c) {
    if (c + 1 < 2) stage((c + 1) & 1, c + 1);
    const bf16x8* Ab = ldsA[c & 1];
    #pragma unroll
    for (int t = 0; t < 2; ++t)
      #pragma unroll
      for (int mf = 0; mf < 4; ++mf) {
        bf16x8 afr = Ab[(t * 4 + kq) * 64 + mf * 16 + lr];
        #pragma unroll
        for (int nf = 0; nf < 2; ++nf)
          acc[mf][nf] = __builtin_amdgcn_mfma_f32_16x16x32_bf16(
              afr, bw[c][t][nf], acc[mf][nf], 0, 0, 0);
      }
    __syncthreads();
  }

  if (by >= 2) {
    #pragma unroll
    for (int nf = 0; nf < 2; ++nf) {
      int n = n0 + nf * 16 + lr - 256;
      #pragma unroll
      for (int mf = 0; mf < 4; ++mf)
        #pragma unroll
        for (int i = 0; i < 4; ++i)
          zbu[(size_t)(m0 + mf * 16 + kq * 4 + i) * 256 + n] =
              f2bf(siluf(acc[mf][nf][i]));
    }
    return;
  }

  #pragma unroll
  for (int nf = 0; nf < 2; ++nf) {
    int ch = wid * 32 + nf * 16 + lr;
    #pragma unroll
    for (int mf = 0; mf < 4; ++mf)
      #pragma unroll
      for (int i = 0; i < 4; ++i)
        xmt[3 + mf * 16 + kq * 4 + i][ch] = f2bf(acc[mf][nf][i]);
  }
  __syncthreads();

  for (int w = tid; w < 384; w += 256) {
    int j = w >> 7, ch = w & 127;
    float a = 0.f;
    if (l0 != 0) {
      const unsigned short* wr = Wn + (size_t)(by * 128 + ch) * 128;
      #pragma unroll 4
      for (int k0 = 0; k0 < 128; k0 += 8) {
        bf16x8 wv = *reinterpret_cast<const bf16x8*>(wr + k0);
        #pragma unroll
        for (int k = 0; k < 8; ++k)
          a = fmaf(bf2f(s3[j][k0 + k]), bf2f((unsigned short)wv[k]), a);
      }
    }
    xmt[j][ch] = f2bf(a);
  }
  __syncthreads();

  const int tg = tid & 15, ch8 = tid >> 4;
  float wr8[8][4], br8[8];
  #pragma unroll
  for (int k = 0; k < 8; ++k) {
    int chl = ch8 * 8 + k;
    wr8[k][0] = cw[chl][0]; wr8[k][1] = cw[chl][1];
    wr8[k][2] = cw[chl][2]; wr8[k][3] = cw[chl][3];
    br8[k] = cbias[chl];
  }
  #pragma unroll
  for (int tk = 0; tk < 4; ++tk) {
    int m = tg * 4 + tk;
    float o[8];
    #pragma unroll
    for (int k = 0; k < 8; ++k) o[k] = br8[k];
    #pragma unroll
    for (int j = 0; j < 4; ++j) {
      uint4 xv = *reinterpret_cast<const uint4*>(&xmt[m + j][ch8 * 8]);
      const unsigned short* xs = reinterpret_cast<const unsigned short*>(&xv);
      #pragma unroll
      for (int k = 0; k < 8; ++k)
        o[k] = fmaf(bf2f(xs[k]), wr8[k][j], o[k]);
    }
    unsigned int pk[4];
    #pragma unroll
    for (int k = 0; k < 4; ++k) {
      unsigned short lo = f2bf(siluf(o[2 * k]));
      unsigned short hi = f2bf(siluf(o[2 * k + 1]));
      pk[k] = (unsigned int)lo | ((unsigned int)hi << 16);
    }
    *reinterpret_cast<uint4*>(
        &xsu[(size_t)(m0 + m) * 256 + by * 128 + ch8 * 8]) =
        *reinterpret_cast<uint4*>(pk);
  }
}

// ---------------- chunked selective scan ------------------------------------
// pass1: inline x_proj (MFMA) -> sh, writes sh to xdb; tree-power dA.
__global__ __launch_bounds__(256) void scan_pass1(
    const unsigned short* __restrict__ xssm,
    const unsigned short* __restrict__ xpw,   // [128][256] bf16, rows>=40 zero
    const float* __restrict__ dtw, const float* __restrict__ dtb,
    const float* __restrict__ An2f,
    unsigned short* __restrict__ Qb, float* __restrict__ S,
    float* __restrict__ xdb)                  // (T,40) f32 out
{
  __shared__ __align__(16) float sh[CL][40];
  const int c = blockIdx.x, b = blockIdx.y;
  const int d = threadIdx.x;
  const int lane = threadIdx.x & 63, wid = threadIdx.x >> 6;
  if (wid < 3) {
    const int col0 = wid * 16;
    const int plr = lane & 15, plk = (lane >> 4) * 8;
    f32x4 pacc = f32x4{0.f, 0.f, 0.f, 0.f};
    const unsigned short* Xrow =
        xssm + ((size_t)b * 4096 + (size_t)c * CL + plr) * 256;
    const unsigned short* Wrow = xpw + (size_t)(col0 + plr) * 256;
    #pragma unroll
    for (int k0 = 0; k0 < 256; k0 += 32) {
      bf16x8 af = *reinterpret_cast<const bf16x8*>(Xrow + k0 + plk);
      bf16x8 bf = *reinterpret_cast<const bf16x8*>(Wrow + k0 + plk);
      pacc = __builtin_amdgcn_mfma_f32_16x16x32_bf16(af, bf, pacc, 0, 0, 0);
    }
    int col = col0 + (lane & 15);
    if (col < 40) {
      #pragma unroll
      for (int i = 0; i < 4; ++i)
        sh[(lane >> 4) * 4 + i][col] = pacc[i];
    }
  }
  float4 w0 = *reinterpret_cast<const float4*>(&dtw[d * 8]);
  float4 w1 = *reinterpret_cast<const float4*>(&dtw[d * 8 + 4]);
  const float bdt = dtb[d];
  float An2[16], h[16];
  {
    const f32x4* a2 = reinterpret_cast<const f32x4*>(&An2f[d * 16]);
    #pragma unroll
    for (int q = 0; q < 4; ++q) {
      f32x4 v = a2[q];
      An2[q * 4 + 0] = v[0]; An2[q * 4 + 1] = v[1];
      An2[q * 4 + 2] = v[2]; An2[q * 4 + 3] = v[3];
    }
  }
  const float An2_0 = An2[0];
  bool usePow = true;
  #pragma unroll
  for (int s = 1; s < 16; ++s)
    usePow = usePow &&
        (fabsf(An2[s] - (float)(s + 1) * An2_0) <= 1e-4f * fabsf(An2[s]));
  #pragma unroll
  for (int s = 0; s < 16; ++s) h[s] = 0.f;
  __syncthreads();

  // persist sh tile for pass2 (de-dup x_proj)
  if (d < CL * 10) {
    reinterpret_cast<float4*>(&xdb[((size_t)b * 4096 + (size_t)c * CL) * 40])[d] =
        reinterpret_cast<const float4*>(&sh[0][0])[d];
  }

  float sdt = 0.f;
  const size_t xbase = ((size_t)b * 4096 + (size_t)c * CL) * 256 + d;
  unsigned short xu = xssm[xbase];
  for (int l = 0; l < CL; ++l) {
    unsigned short xun = (l + 1 < CL) ? xssm[xbase + (size_t)(l + 1) * 256]
                                      : (unsigned short)0;
    const float4* row = reinterpret_cast<const float4*>(sh[l]);
    float4 r0 = row[0], r1 = row[1];
    float acc = bdt;
    acc = fmaf(r0.x, w0.x, acc); acc = fmaf(r0.y, w0.y, acc);
    acc = fmaf(r0.z, w0.z, acc); acc = fmaf(r0.w, w0.w, acc);
    acc = fmaf(r1.x, w1.x, acc); acc = fmaf(r1.y, w1.y, acc);
    acc = fmaf(r1.z, w1.z, acc); acc = fmaf(r1.w, w1.w, acc);
    float dt = (acc > 20.f) ? acc : __logf(1.f + __expf(acc));
    sdt += dt;
    float dtx = dt * bf2f(xu);
    if (usePow) {
      float r1p = __builtin_amdgcn_exp2f(dt * An2_0);
      float r2 = r1p * r1p, r3 = r2 * r1p, r4 = r2 * r2;
      float pj[4] = {r1p, r2, r3, r4};
      float base = 1.f;
      #pragma unroll
      for (int q = 0; q < 4; ++q) {
        float4 Bq = row[2 + q];
        float bb4[4] = {Bq.x, Bq.y, Bq.z, Bq.w};
        #pragma unroll
        for (int j = 0; j < 4; ++j) {
          int s = q * 4 + j;
          h[s] = fmaf(base * pj[j], h[s], dtx * bb4[j]);
        }
        base *= r4;
      }
    } else {
      #pragma unroll
      for (int q = 0; q < 4; ++q) {
        float4 Bq = row[2 + q];
        float bb4[4] = {Bq.x, Bq.y, Bq.z, Bq.w};
        #pragma unroll
        for (int j = 0; j < 4; ++j) {
          int s = q * 4 + j;
          float dA = __builtin_amdgcn_exp2f(dt * An2[s]);
          h[s] = fmaf(dA, h[s], dtx * bb4[j]);
        }
      }
    }
    xu = xun;
  }
  unsigned int pk[8];
  #pragma unroll
  for (int k = 0; k < 8; ++k)
    pk[k] = (unsigned int)f2bf(h[2 * k]) | ((unsigned int)f2bf(h[2 * k + 1]) << 16);
  uint4* qp = reinterpret_cast<uint4*>(
      &Qb[(((size_t)b * NC + c) * 256 + d) * 16]);
  qp[0] = *reinterpret_cast<uint4*>(pk);
  qp[1] = *reinterpret_cast<uint4*>(pk + 4);
  S[((size_t)b * NC + c) * 256 + d] = sdt;
}

// ---------------- coalesced LDS-buffered combine ----------------------------
__global__ __launch_bounds__(256) void scan_combine(
    unsigned short* __restrict__ Qb, const float* __restrict__ S,
    const float* __restrict__ An2f)
{
  constexpr int TC = 64;
  __shared__ unsigned short qt[TC][256];
  __shared__ float mt[TC][256];
  const int b = blockIdx.x >> 4, dsg = blockIdx.x & 15;
  const int tid = threadIdx.x;
  const int ds = dsg * 256 + tid;      // d*16+s
  const int d = ds >> 4;
  const float An2 = An2f[ds];
  float h = 0.f;
  for (int ct = 0; ct < NC; ct += TC) {
    #pragma unroll 8
    for (int r = 0; r < TC; ++r) {
      int c = ct + r;
      qt[r][tid] = Qb[(size_t)(b * NC + c) * 4096 + ds];
      mt[r][tid] = __builtin_amdgcn_exp2f(
          An2 * S[(size_t)(b * NC + c) * 256 + d]);
    }
    #pragma unroll 8
    for (int r = 0; r < TC; ++r) {
      float q = bf2f(qt[r][tid]);
      qt[r][tid] = f2bf(h);
      h = fmaf(mt[r][tid], h, q);
    }
    #pragma unroll 8
    for (int r = 0; r < TC; ++r)
      Qb[(size_t)(b * NC + ct + r) * 4096 + ds] = qt[r][tid];
  }
}

// ---------------- pass2 + out_proj + LN + NCHW transpose, fused -------------
// Grid (64, 8), 512 threads. Block covers 4 chunks = 64 tokens of batch b.
// Scan: each 256-thread half scans 2 chunks; y -> LDS ybuf[64][264] bf16.
// GEMM: 8 waves, N=16/wave, K=256 from ybuf; LN (8 thr/token); NCHW write.
// fp32 LN buffer buf[64][132] ALIASES ybuf (both 33,792 B, barrier-separated).
__global__ __launch_bounds__(512) void scan_pass2_fused(
    const unsigned short* __restrict__ xssm,
    const float* __restrict__ xdb,           // (T,40) f32 from pass1
    const unsigned short* __restrict__ zb,   // silu(z) bf16
    const float* __restrict__ dtw, const float* __restrict__ dtb,
    const float* __restrict__ An2f, const float* __restrict__ Dp,
    const unsigned short* __restrict__ Hstart,  // Qb (bf16 h_start)
    const unsigned short* __restrict__ Wn,      // wout [128][256] bf16
    const float* __restrict__ lg, const float* __restrict__ lb,
    float* __restrict__ out)                    // [8][128][64][64]
{
  __shared__ __align__(16) float sh[4][CL][40];     // 10,240 B
  __shared__ __align__(16) char yb_raw[64 * 264 * 2];  // 33,792 B (ybuf|buf)
  unsigned short (*ybuf)[264] =
      reinterpret_cast<unsigned short(*)[264]>(yb_raw);
  float (*buf)[132] = reinterpret_cast<float(*)[132]>(yb_raw);

  const int cg = blockIdx.x, b = blockIdx.y;
  const int c0 = cg * 4;
  const int tid = threadIdx.x;
  const int lane = tid & 63, wid = tid >> 6;
  const int d = tid & 255;
  const int half = tid >> 8;

  // stage 4 chunk xdb tiles (640 float4)
  for (int i = tid; i < 4 * CL * 10; i += 512) {
    reinterpret_cast<float4*>(&sh[0][0][0])[i] =
        reinterpret_cast<const float4*>(
            &xdb[((size_t)b * 4096 + (size_t)c0 * CL) * 40])[i];
  }

  float4 w0 = *reinterpret_cast<const float4*>(&dtw[d * 8]);
  float4 w1 = *reinterpret_cast<const float4*>(&dtw[d * 8 + 4]);
  const float bdt = dtb[d];
  const float Dd = Dp[d];
  float An2[16];
  {
    const f32x4* a2 = reinterpret_cast<const f32x4*>(&An2f[d * 16]);
    #pragma unroll
    for (int q = 0; q < 4; ++q) {
      f32x4 v = a2[q];
      An2[q * 4 + 0] = v[0]; An2[q * 4 + 1] = v[1];
      An2[q * 4 + 2] = v[2]; An2[q * 4 + 3] = v[3];
    }
  }
  const float An2_0 = An2[0];
  bool usePow = true;
  #pragma unroll
  for (int s = 1; s < 16; ++s)
    usePow = usePow &&
        (fabsf(An2[s] - (float)(s + 1) * An2_0) <= 1e-4f * fabsf(An2[s]));
  __syncthreads();

  // ---- scan phase: half h scans chunks c0+2h, c0+2h+1 ----
  for (int chh = 0; chh < 2; ++chh) {
    const int ch = half * 2 + chh;
    const int c = c0 + ch;
    float h[16];
    {
      const uint4* hp = reinterpret_cast<const uint4*>(
          &Hstart[(((size_t)b * NC + c) * 256 + d) * 16]);
      uint4 h0 = hp[0], h1 = hp[1];
      const unsigned short* hs = reinterpret_cast<const unsigned short*>(&h0);
      #pragma unroll
      for (int s = 0; s < 8; ++s) h[s] = bf2f(hs[s]);
      const unsigned short* hs2 = reinterpret_cast<const unsigned short*>(&h1);
      #pragma unroll
      for (int s = 0; s < 8; ++s) h[8 + s] = bf2f(hs2[s]);
    }
    const size_t xbase = ((size_t)b * 4096 + (size_t)c * CL) * 256 + d;
    unsigned short xu = xssm[xbase], zu = zb[xbase];
    for (int l = 0; l < CL; ++l) {
      unsigned short xun = 0, zun = 0;
      if (l + 1 < CL) {
        xun = xssm[xbase + (size_t)(l + 1) * 256];
        zun = zb[xbase + (size_t)(l + 1) * 256];
      }
      const float4* row = reinterpret_cast<const float4*>(sh[ch][l]);
      float4 r0 = row[0], r1 = row[1];
      float acc = bdt;
      acc = fmaf(r0.x, w0.x, acc); acc = fmaf(r0.y, w0.y, acc);
      acc = fmaf(r0.z, w0.z, acc); acc = fmaf(r0.w, w0.w, acc);
      acc = fmaf(r1.x, w1.x, acc); acc = fmaf(r1.y, w1.y, acc);
      acc = fmaf(r1.z, w1.z, acc); acc = fmaf(r1.w, w1.w, acc);
      float dt = (acc > 20.f) ? acc : __logf(1.f + __expf(acc));
      float xv = bf2f(xu);
      float dtx = dt * xv;
      float yq[4] = {0.f, 0.f, 0.f, 0.f};
      if (usePow) {
        float r1p = __builtin_amdgcn_exp2f(dt * An2_0);
        float r2 = r1p * r1p, r3 = r2 * r1p, r4 = r2 * r2;
        float pj[4] = {r1p, r2, r3, r4};
        float base = 1.f;
        #pragma unroll
        for (int q = 0; q < 4; ++q) {
          float4 Bq = row[2 + q], Cq = row[6 + q];
          float bb4[4] = {Bq.x, Bq.y, Bq.z, Bq.w};
          float cc4[4] = {Cq.x, Cq.y, Cq.z, Cq.w};
          #pragma unroll
          for (int j = 0; j < 4; ++j) {
            int s = q * 4 + j;
            h[s] = fmaf(base * pj[j], h[s], dtx * bb4[j]);
            yq[q] = fmaf(h[s], cc4[j], yq[q]);
          }
          base *= r4;
        }
      } else {
        #pragma unroll
        for (int q = 0; q < 4; ++q) {
          float4 Bq = row[2 + q], Cq = row[6 + q];
          float bb4[4] = {Bq.x, Bq.y, Bq.z, Bq.w};
          float cc4[4] = {Cq.x, Cq.y, Cq.z, Cq.w};
          #pragma unroll
          for (int j = 0; j < 4; ++j) {
            int s = q * 4 + j;
            float dA = __builtin_amdgcn_exp2f(dt * An2[s]);
            h[s] = fmaf(dA, h[s], dtx * bb4[j]);
            yq[q] = fmaf(h[s], cc4[j], yq[q]);
          }
        }
      }
      float y = (yq[0] + yq[1]) + (yq[2] + yq[3]);
      y = (y + Dd * xv) * bf2f(zu);   // z already silu'd
      ybuf[ch * CL + l][d] = f2bf(y);
      xu = xun; zu = zun;
    }
  }
  __syncthreads();

  // ---- out_proj GEMM: 8 waves, wave w -> N cols [w*16, w*16+16) ----
  const int n0g = wid * 16;
  const int lr = lane & 15, kq = lane >> 4, lk = kq * 8;
  bf16x8 bwv[4][2];
  #pragma unroll
  for (int c = 0; c < 4; ++c)
    #pragma unroll
    for (int t = 0; t < 2; ++t)
      bwv[c][t] = *reinterpret_cast<const bf16x8*>(
          Wn + (size_t)(n0g + lr) * 256 + c * 64 + t * 32 + lk);

  f32x4 acc[4];
  #pragma unroll
  for (int i = 0; i < 4; ++i) acc[i] = f32x4{0.f, 0.f, 0.f, 0.f};
  #pragma unroll
  for (int c = 0; c < 4; ++c)
    #pragma unroll
    for (int t = 0; t < 2; ++t) {
      const int kc = c * 64 + t * 32 + lk;
      #pragma unroll
      for (int mf = 0; mf < 4; ++mf) {
        bf16x8 afr = *reinterpret_cast<const bf16x8*>(&ybuf[mf * 16 + lr][kc]);
        acc[mf] = __builtin_amdgcn_mfma_f32_16x16x32_bf16(
            afr, bwv[c][t], acc[mf], 0, 0, 0);
      }
    }
  __syncthreads();

  // ---- write acc into fp32 buf (aliases ybuf; all reads done) ----
  {
    int n = n0g + lr;
    #pragma unroll
    for (int mf = 0; mf < 4; ++mf)
      #pragma unroll
      for (int i = 0; i < 4; ++i)
        buf[mf * 16 + kq * 4 + i][n] = acc[mf][i];
  }
  __syncthreads();

  // ---- LayerNorm: 8 threads/token x 16 ch ----
  {
    const int tt = tid >> 3, q = tid & 7;
    float s = 0.f, sq = 0.f;
    #pragma unroll
    for (int i = 0; i < 16; ++i) {
      float v = buf[tt][q * 16 + i];
      s += v; sq += v * v;
    }
    s  += __shfl_xor(s, 1);  s  += __shfl_xor(s, 2);  s  += __shfl_xor(s, 4);
    sq += __shfl_xor(sq, 1); sq += __shfl_xor(sq, 2); sq += __shfl_xor(sq, 4);
    float mu = s * (1.f / 128.f);
    float var = sq * (1.f / 128.f) - mu * mu;
    float rstd = rsqrtf(fmaxf(var, 0.f) + 1e-5f);
    #pragma unroll
    for (int i = 0; i < 16; ++i) {
      int ch = q * 16 + i;
      buf[tt][ch] = (buf[tt][ch] - mu) * rstd * lg[ch] + lb[ch];
    }
  }
  __syncthreads();

  // ---- NCHW write (coalesced over 64 consecutive l) ----
  const int l0 = cg * 64;
  for (int idx = tid; idx < 64 * 128; idx += 512) {
    int ch = idx >> 6, t2 = idx & 63;
    out[((size_t)b * 128 + ch) * 4096 + l0 + t2] = buf[t2][ch];
  }
}

// ---------------------------------------------------------------------------
extern "C" void kernel_launch(void* const* d_in, const int* in_sizes, int n_in,
                              void* d_out, int out_size, void* d_ws, size_t ws_size,
                              hipStream_t stream) {
  const float* x        = (const float*)d_in[0];
  const float* conv1_w  = (const float*)d_in[1];
  const float* conv1_b  = (const float*)d_in[2];
  const float* bn1_g    = (const float*)d_in[3];
  const float* bn1_b    = (const float*)d_in[4];
  const float* bn1_m    = (const float*)d_in[5];
  const float* bn1_v    = (const float*)d_in[6];
  const float* conv2_w  = (const float*)d_in[7];
  const float* conv2_b  = (const float*)d_in[8];
  const float* bn2_g    = (const float*)d_in[9];
  const float* bn2_b    = (const float*)d_in[10];
  const float* bn2_m    = (const float*)d_in[11];
  const float* bn2_v    = (const float*)d_in[12];
  const float* in_proj_w  = (const float*)d_in[13];  // (512,128)
  const float* conv1d_w   = (const float*)d_in[14];  // (256,1,4)
  const float* conv1d_b   = (const float*)d_in[15];
  const float* x_proj_w   = (const float*)d_in[16];  // (40,256)
  const float* dt_proj_w  = (const float*)d_in[17];  // (256,8)
  const float* dt_proj_b  = (const float*)d_in[18];
  const float* A_log      = (const float*)d_in[19];  // (256,16)
  const float* Dp         = (const float*)d_in[20];  // (256)
  const float* out_proj_w = (const float*)d_in[21];  // (128,256)
  const float* ln_g       = (const float*)d_in[22];
  const float* ln_b       = (const float*)d_in[23];
  float* out = (float*)d_out;

  float* ws_f = (float*)d_ws;
  // workspace (float units), lifetime-reuse
  unsigned short* xbp  = (unsigned short*)ws_f;          // [8][66][66][64] (pre)
  float*          xdb  = ws_f + 4194304;                 // T*40 f32 (pass1->pass2)
  float*          Sbuf = ws_f + 5505024;                 // B*NC*256 f32
  unsigned short* zbu  = (unsigned short*)(ws_f + 8388608);   // T*256 bf16 silu(z)
  unsigned short* xsu  = (unsigned short*)(ws_f + 12582912);  // T*256 bf16
  unsigned short* h1p  = (unsigned short*)(ws_f + 16777216);  // [8][66][66][128]
  unsigned short* seqb = (unsigned short*)(ws_f + 19007488);  // [T][128]
  unsigned short* Qb   = (unsigned short*)(ws_f + 16777216);  // B*NC*256*16 bf16
  unsigned short* wb1  = (unsigned short*)(ws_f + 25165824);
  unsigned short* wb2  = (unsigned short*)(ws_f + 25202688);
  unsigned short* win  = (unsigned short*)(ws_f + 25276416);
  unsigned short* wout = (unsigned short*)(ws_f + 25309184);
  unsigned short* xpwb = (unsigned short*)(ws_f + 25325568);
  float*          An2f = ws_f + 25341952;

  prologue<<<1920, 256, 0, stream>>>(
      x, xbp, conv1_w, conv2_w, in_proj_w, out_proj_w, x_proj_w, A_log,
      wb1, wb2, win, wout, xpwb, An2f, h1p);

  conv_mfma<64, 1><<<dim3(64, 8), 512, 0, stream>>>(
      xbp, wb1, conv1_b, bn1_g, bn1_b, bn1_m, bn1_v, h1p);
  conv_mfma<128, 0><<<dim3(64, 8), 512, 0, stream>>>(
      h1p, wb2, conv2_b, bn2_g, bn2_b, bn2_m, bn2_v, seqb);

  inproj_fused<<<dim3(512, 4), 256, 0, stream>>>(
      seqb, win, conv1d_w, conv1d_b, xsu, zbu);

  scan_pass1<<<dim3(NC, 8), 256, 0, stream>>>(
      xsu, xpwb, dt_proj_w, dt_proj_b, An2f, Qb, Sbuf, xdb);
  scan_combine<<<128, 256, 0, stream>>>(Qb, Sbuf, An2f);
  scan_pass2_fused<<<dim3(64, 8), 512, 0, stream>>>(
      xsu, xdb, zbu, dt_proj_w, dt_proj_b, An2f, Dp, Qb,
      wout, ln_g, ln_b, out);
}